// Round 15
// baseline (54.788 us; speedup 1.0000x reference)
//
#include <hip/hip_runtime.h>

// ExponentialUnitNorm: s_t = 0.01*|x_t| + 0.99*s_{t-1};  out_t = x_t / sqrt(s_t)
// x: [B=16, C=2, T=1000, F=481, 2] fp32.  init_state: [1,1,F,1] fp32.
//
// R14 = R13 (LDS-stash superstep scan) + T14 async-STAGE split:
// loads for superstep s+1 are ISSUED during phase B of superstep s (between
// prefix and apply), so HBM read latency hides under the apply/write stream
// and the end barrier. R13 post-mortem: HBM traffic is only ~180MB (29us
// floor) but dur=47us — the gap is per-superstep barrier-exposed load
// latency (~0.5-1us x 20 steps), which this pipeline removes.
// Structure otherwise identical to R13:
//   block=(bc, 64-wide f-tile), 1024 thr = 16 waves; superstep=100 rows;
//   wave w owns 7 rows (w<4) / 6 (w>=4). Per superstep:
//     stash-write + partial Cl -> lds_c ; barrier ; prefix + carry publish ;
//     ISSUE next loads ; apply from stash -> out ; barrier.

#define EPS_F 1e-14f

constexpr int B = 16, C = 2, T = 1000, F = 481;
constexpr int BC = B * C;        // 32
constexpr int FW = 64;           // f-tile width = one wave
constexpr int NTILE = 8;         // ceil(481/64)
constexpr int WV = 16;           // waves per block
constexpr int RSTEP = 100;       // rows per superstep
constexpr int NSUP = T / RSTEP;  // 10
constexpr int ROWS = F * 2;      // 962 floats per t-row
constexpr int VMAX = 7;          // max rows per wave per superstep

__device__ __forceinline__ int wbase(int w) { return (w < 4) ? 7 * w : 28 + 6 * (w - 4); }
__device__ __forceinline__ int wlen(int w)  { return (w < 4) ? 7 : 6; }

__global__ __launch_bounds__(1024)
void k_fused(const float* __restrict__ x, const float* __restrict__ init_state,
             float* __restrict__ out) {
    __shared__ float2 stash[RSTEP][FW];   // 51200 B
    __shared__ float  lds_c[WV][FW];      // 4096 B
    __shared__ float  carry[2][FW];       // 512 B

    const int fx   = threadIdx.x & (FW - 1);
    const int w    = threadIdx.x >> 6;
    const int bc   = blockIdx.x & (BC - 1);
    const int tile = blockIdx.x >> 5;
    const int f    = tile * FW + fx;
    const bool act = (f < F);

    double p = 1.0;
    for (int i = 0; i < 6; ++i) p *= 0.99;
    const float A6 = (float)p;
    const float A7 = (float)(p * 0.99);

    if (threadIdx.x < FW) carry[0][fx] = act ? init_state[f] : 1.0f;

    const int rb     = wbase(w);
    const int len    = wlen(w);
    const float aOwn = (w < 4) ? A7 : A6;

    // prologue: issue superstep-0 loads
    float2 r[VMAX];
    {
        const float* xp = x + ((size_t)(bc * T + rb) * F + f) * 2;
#pragma unroll
        for (int j = 0; j < VMAX; ++j)
            if (j < len)
                r[j] = act ? *(const float2*)(xp + (size_t)j * ROWS)
                           : make_float2(0.0f, 0.0f);
    }

    for (int s = 0; s < NSUP; ++s) {
        const int par = s & 1;

        // ---- stash write + zero-init partial sum (r[] already in flight) ----
        float Cl = 0.0f;
#pragma unroll
        for (int j = 0; j < VMAX; ++j) {
            if (j < len) {
                stash[rb + j][fx] = r[j];
                float m = fmaxf(fmaf(r[j].x, r[j].x, r[j].y * r[j].y), EPS_F);
                Cl = fmaf(0.99f, Cl, 0.01f * __builtin_amdgcn_sqrtf(m));
            }
        }
        lds_c[w][fx] = Cl;
        __syncthreads();  // A: stash + lds_c (+ carry) visible

        // ---- chunk-init prefix + carry publish ----
        float sloc = carry[par][fx];
#pragma unroll
        for (int jw = 0; jw < WV - 1; ++jw) {
            const float aL = (jw < 4) ? A7 : A6;
            if (jw < w) sloc = fmaf(aL, sloc, lds_c[jw][fx]);
        }
        if (w == WV - 1) carry[par ^ 1][fx] = fmaf(aOwn, sloc, Cl);

        // ---- ISSUE next superstep's loads (fly during apply + barrier) ----
        if (s + 1 < NSUP) {
            const float* xn = x + ((size_t)(bc * T + (s + 1) * RSTEP + rb) * F + f) * 2;
#pragma unroll
            for (int j = 0; j < VMAX; ++j)
                if (j < len)
                    r[j] = act ? *(const float2*)(xn + (size_t)j * ROWS)
                               : make_float2(0.0f, 0.0f);
        }

        // ---- apply from stash, write out ----
        float* op = out + ((size_t)(bc * T + s * RSTEP + rb) * F + f) * 2;
#pragma unroll
        for (int j = 0; j < VMAX; ++j) {
            if (j < len) {
                float2 v = stash[rb + j][fx];
                float m = fmaxf(fmaf(v.x, v.x, v.y * v.y), EPS_F);
                sloc = fmaf(0.99f, sloc, 0.01f * __builtin_amdgcn_sqrtf(m));
                const float inv = __builtin_amdgcn_rsqf(sloc);
                float2 o;
                o.x = v.x * inv;
                o.y = v.y * inv;
                if (act) *(float2*)(op + (size_t)j * ROWS) = o;
            }
        }
        __syncthreads();  // B: stash consumed; next superstep may overwrite
    }
}

extern "C" void kernel_launch(void* const* d_in, const int* in_sizes, int n_in,
                              void* d_out, int out_size, void* d_ws, size_t ws_size,
                              hipStream_t stream) {
    const float* x          = (const float*)d_in[0];
    const float* init_state = (const float*)d_in[1];
    float* out = (float*)d_out;

    k_fused<<<dim3(NTILE * BC), 1024, 0, stream>>>(x, init_state, out);
}

// Round 16
// 41.984 us; speedup vs baseline: 1.3050x; 1.3050x over previous
//
#include <hip/hip_runtime.h>

// ExponentialUnitNorm: s_t = 0.01*|x_t| + 0.99*s_{t-1};  out_t = x_t / sqrt(s_t)
// x: [B=16, C=2, T=1000, F=481, 2] fp32.  init_state: [1,1,F,1] fp32.
//
// R15 = R10 geometry (512 thr = 8 waves, 25 rows/wave, 5x200-row supersteps,
// block = (bc, 64-wide f-tile)) + three fixes from R6/R10/R14 post-mortems:
//  1) TRUE register stash, double-buffered (vA/vB), with per-value
//     asm("":"+v") pins — compiler cannot rematerialize/sink the loads
//     (VGPR_Count is the diagnostic: expect ~120-170, not 40).
//  2) superstep s+1's loads ISSUED during phase B of s (before apply/write),
//     so HBM latency hides under the store stream.
//  3) lgkm-only barriers (s_waitcnt lgkmcnt(0) + raw s_barrier) instead of
//     __syncthreads() — __syncthreads drains vmcnt(0), which would kill the
//     in-flight preloads; LDS (lds_c/carry) correctness needs only lgkmcnt.
// x is read from HBM exactly once; no L3-reuse-window dependence.

#define EPS_F 1e-14f

constexpr int B = 16, C = 2, T = 1000, F = 481;
constexpr int BC = B * C;        // 32
constexpr int FW = 64;           // f-tile width = one wave
constexpr int NTILE = 8;         // ceil(481/64)
constexpr int WV = 8;            // waves per block
constexpr int RW = 25;           // rows per wave per superstep
constexpr int RSTEP = WV * RW;   // 200
constexpr int NSUP = T / RSTEP;  // 5 (exact, no tails)
constexpr int ROWS = F * 2;      // 962 floats per t-row

#define LOADG(buf, sidx)                                                     \
  {                                                                          \
    const float* _xp = xp0 + (size_t)((sidx) * RSTEP) * ROWS;                \
    _Pragma("unroll")                                                        \
    for (int j = 0; j < RW; ++j)                                             \
      (buf)[j] = act ? *(const float2*)(_xp + (size_t)j * ROWS)              \
                     : make_float2(0.0f, 0.0f);                              \
    _Pragma("unroll")                                                        \
    for (int j = 0; j < RW; ++j)                                             \
      asm volatile("" : "+v"((buf)[j].x), "+v"((buf)[j].y));                 \
  }

#define SUPERSTEP(sidx, cur, nxt, do_preload)                                \
  {                                                                          \
    float Cl = 0.0f;                                                         \
    _Pragma("unroll")                                                        \
    for (int j = 0; j < RW; ++j) {                                           \
      float m = fmaxf(fmaf((cur)[j].x, (cur)[j].x, (cur)[j].y * (cur)[j].y), \
                      EPS_F);                                                \
      Cl = fmaf(0.99f, Cl, 0.01f * __builtin_amdgcn_sqrtf(m));               \
    }                                                                        \
    lds_c[w][fx] = Cl;                                                       \
    asm volatile("s_waitcnt lgkmcnt(0)" ::: "memory");                       \
    __builtin_amdgcn_s_barrier();                                            \
    const int par = (sidx) & 1;                                              \
    float sloc = carry[par][fx];                                             \
    _Pragma("unroll")                                                        \
    for (int jw = 0; jw < WV - 1; ++jw)                                      \
      if (jw < w) sloc = fmaf(A25, sloc, lds_c[jw][fx]);                     \
    if (w == WV - 1) carry[par ^ 1][fx] = fmaf(A25, sloc, Cl);               \
    if (do_preload) LOADG(nxt, (sidx) + 1);                                  \
    asm volatile("" ::: "memory");                                           \
    float* _op = op0 + (size_t)((sidx) * RSTEP) * ROWS;                      \
    _Pragma("unroll")                                                        \
    for (int j = 0; j < RW; ++j) {                                           \
      float2 v = (cur)[j];                                                   \
      float m = fmaxf(fmaf(v.x, v.x, v.y * v.y), EPS_F);                     \
      sloc = fmaf(0.99f, sloc, 0.01f * __builtin_amdgcn_sqrtf(m));           \
      const float inv = __builtin_amdgcn_rsqf(sloc);                         \
      float2 o;                                                              \
      o.x = v.x * inv;                                                       \
      o.y = v.y * inv;                                                       \
      if (act) *(float2*)(_op + (size_t)j * ROWS) = o;                       \
    }                                                                        \
    asm volatile("s_waitcnt lgkmcnt(0)" ::: "memory");                       \
    __builtin_amdgcn_s_barrier();                                            \
  }

__global__ __launch_bounds__(512, 2)
void k_fused(const float* __restrict__ x, const float* __restrict__ init_state,
             float* __restrict__ out) {
    __shared__ float lds_c[WV][FW];
    __shared__ float carry[2][FW];

    const int fx   = threadIdx.x & (FW - 1);
    const int w    = threadIdx.x >> 6;
    const int bc   = blockIdx.x & (BC - 1);
    const int tile = blockIdx.x >> 5;
    const int f    = tile * FW + fx;
    const bool act = (f < F);

    double q = 1.0;
    for (int i = 0; i < RW; ++i) q *= 0.99;
    const float A25 = (float)q;

    if (threadIdx.x < FW) carry[0][fx] = act ? init_state[f] : 1.0f;

    // per-thread base pointers for (bc, wave-row-base, f)
    const float* xp0 = x   + ((size_t)(bc * T + w * RW) * F + f) * 2;
    float*       op0 = out + ((size_t)(bc * T + w * RW) * F + f) * 2;

    float2 vA[RW], vB[RW];

    LOADG(vA, 0);
    SUPERSTEP(0, vA, vB, true);
    SUPERSTEP(1, vB, vA, true);
    SUPERSTEP(2, vA, vB, true);
    SUPERSTEP(3, vB, vA, true);
    SUPERSTEP(4, vA, vB, false);
}

extern "C" void kernel_launch(void* const* d_in, const int* in_sizes, int n_in,
                              void* d_out, int out_size, void* d_ws, size_t ws_size,
                              hipStream_t stream) {
    const float* x          = (const float*)d_in[0];
    const float* init_state = (const float*)d_in[1];
    float* out = (float*)d_out;

    k_fused<<<dim3(NTILE * BC), 512, 0, stream>>>(x, init_state, out);
}

// Round 17
// 41.767 us; speedup vs baseline: 1.3117x; 1.0052x over previous
//
#include <hip/hip_runtime.h>

// ExponentialUnitNorm: s_t = 0.01*|x_t| + 0.99*s_{t-1};  out_t = x_t / sqrt(s_t)
// x: [B=16, C=2, T=1000, F=481, 2] fp32.  init_state: [1,1,F,1] fp32.
//
// R16 = R15 + full manual load-issue/wait control (T3/T4-style):
//  - loads are inline-asm global_load_dwordx2 (opaque to compiler: cannot be
//    sunk/rematerialized, no auto-waitcnt) into a double-buffered register
//    stash (vA/vB, 25 float2 each);
//  - superstep s+1's 25 loads are ISSUED in phase B of s, BEFORE the 25
//    out-stores (order pinned by memory clobbers);
//  - the WAIT is a counted `s_waitcnt vmcnt(25)` at the TOP of superstep s+1:
//    the 25 newest outstanding ops are s's stores, so <=25 outstanding ==
//    all loads retired. Loads thus fly across the store stream AND the
//    lgkm-only barrier (vmcnt NOT drained at barriers).
//  - rule #18: sched_barrier(0) after each waitcnt so register-only VALU
//    consumers can't hoist above the wait.
// Geometry: R10/R15's — block=(bc, 64-wide f-tile), 512 thr = 8 waves,
// wave owns 25 rows, 5x200-row supersteps, no tails. x read exactly once.

#define EPS_F 1e-14f

constexpr int B = 16, C = 2, T = 1000, F = 481;
constexpr int BC = B * C;        // 32
constexpr int FW = 64;           // f-tile width = one wave
constexpr int NTILE = 8;         // ceil(481/64)
constexpr int WV = 8;            // waves per block
constexpr int RW = 25;           // rows per wave per superstep
constexpr int RSTEP = WV * RW;   // 200
constexpr int NSUP = T / RSTEP;  // 5 (exact)
constexpr int ROWS = F * 2;      // 962 floats per t-row

static_assert(RW == 25, "vmcnt(25) literal below assumes RW==25");

__device__ __forceinline__ float2 gload2(const float* p) {
    float2 r;
    asm volatile("global_load_dwordx2 %0, %1, off"
                 : "=v"(r) : "v"(p) : "memory");
    return r;
}

// wait until at most `n` vmem ops outstanding, then fence the scheduler so
// dependent register-only VALU can't hoist above the wait (rule #18).
#define WAITV(n)                                                   \
  do {                                                             \
    asm volatile("s_waitcnt vmcnt(" #n ")" ::: "memory");          \
    __builtin_amdgcn_sched_barrier(0);                             \
  } while (0)

#define LOADG(buf, sidx)                                           \
  {                                                                \
    const float* _xp = xp0 + (size_t)((sidx) * RSTEP) * ROWS;      \
    _Pragma("unroll")                                              \
    for (int j = 0; j < RW; ++j)                                   \
      (buf)[j] = gload2(_xp + (size_t)j * ROWS);                   \
  }

#define STEP(sidx, cur, nxt, do_preload)                                     \
  {                                                                          \
    float Cl = 0.0f;                                                         \
    _Pragma("unroll")                                                        \
    for (int j = 0; j < RW; ++j) {                                           \
      float m = fmaxf(fmaf((cur)[j].x, (cur)[j].x, (cur)[j].y * (cur)[j].y), \
                      EPS_F);                                                \
      Cl = fmaf(0.99f, Cl, 0.01f * __builtin_amdgcn_sqrtf(m));               \
    }                                                                        \
    lds_c[w][fx] = Cl;                                                       \
    asm volatile("s_waitcnt lgkmcnt(0)" ::: "memory");                       \
    __builtin_amdgcn_s_barrier();                                            \
    const int par = (sidx) & 1;                                              \
    float sloc = carry[par][fx];                                             \
    _Pragma("unroll")                                                        \
    for (int jw = 0; jw < WV - 1; ++jw)                                      \
      if (jw < w) sloc = fmaf(A25, sloc, lds_c[jw][fx]);                     \
    if (w == WV - 1) carry[par ^ 1][fx] = fmaf(A25, sloc, Cl);               \
    if (do_preload) LOADG(nxt, (sidx) + 1);                                  \
    float* _op = op0 + (size_t)((sidx) * RSTEP) * ROWS;                      \
    _Pragma("unroll")                                                        \
    for (int j = 0; j < RW; ++j) {                                           \
      float2 v = (cur)[j];                                                   \
      float m = fmaxf(fmaf(v.x, v.x, v.y * v.y), EPS_F);                     \
      sloc = fmaf(0.99f, sloc, 0.01f * __builtin_amdgcn_sqrtf(m));           \
      const float inv = __builtin_amdgcn_rsqf(sloc);                         \
      float2 o;                                                              \
      o.x = v.x * inv;                                                       \
      o.y = v.y * inv;                                                       \
      if (act) *(float2*)(_op + (size_t)j * ROWS) = o;                       \
    }                                                                        \
    asm volatile("s_waitcnt lgkmcnt(0)" ::: "memory");                       \
    __builtin_amdgcn_s_barrier();                                            \
  }

__global__ __launch_bounds__(512, 2)
void k_fused(const float* __restrict__ x, const float* __restrict__ init_state,
             float* __restrict__ out) {
    __shared__ float lds_c[WV][FW];
    __shared__ float carry[2][FW];

    const int fx   = threadIdx.x & (FW - 1);
    const int w    = threadIdx.x >> 6;
    const int bc   = blockIdx.x & (BC - 1);
    const int tile = blockIdx.x >> 5;
    const int f    = tile * FW + fx;
    const bool act = (f < F);
    const int fc   = act ? f : (F - 1);   // clamped for loads (no OOB)

    double q = 1.0;
    for (int i = 0; i < RW; ++i) q *= 0.99;
    const float A25 = (float)q;

    if (threadIdx.x < FW) carry[0][fx] = act ? init_state[f] : 1.0f;

    const float* xp0 = x   + ((size_t)(bc * T + w * RW) * F + fc) * 2;
    float*       op0 = out + ((size_t)(bc * T + w * RW) * F + f) * 2;

    float2 vA[RW], vB[RW];

    LOADG(vA, 0);
    WAITV(0);  STEP(0, vA, vB, true);
    WAITV(25); STEP(1, vB, vA, true);
    WAITV(25); STEP(2, vA, vB, true);
    WAITV(25); STEP(3, vB, vA, true);
    WAITV(25); STEP(4, vA, vB, false);
}

extern "C" void kernel_launch(void* const* d_in, const int* in_sizes, int n_in,
                              void* d_out, int out_size, void* d_ws, size_t ws_size,
                              hipStream_t stream) {
    const float* x          = (const float*)d_in[0];
    const float* init_state = (const float*)d_in[1];
    float* out = (float*)d_out;

    k_fused<<<dim3(NTILE * BC), 512, 0, stream>>>(x, init_state, out);
}

// Round 18
// 41.053 us; speedup vs baseline: 1.3346x; 1.0174x over previous
//
#include <hip/hip_runtime.h>

// ExponentialUnitNorm: s_t = 0.01*|x_t| + 0.99*s_{t-1};  out_t = x_t / sqrt(s_t)
// x: [B=16, C=2, T=1000, F=481, 2] fp32.  init_state: [1,1,F,1] fp32.
//
// R17 = R16 with HALF the barriers: lds_c is double-buffered (lds_c[par]),
// so the end-of-superstep WAR barrier is deleted — one s_barrier per
// superstep (5 total). Wave-drift proof: a wave writing lds_c[par] in
// superstep s+2 has passed bar_{s+1}; every wave's reads of lds_c[par] in
// superstep s precede its own arrival at bar_{s+1}. carry ping-pong
// (write par^1 in s, read par^1 in s+1 after bar_{s+1}) likewise safe.
// Loads: inline-asm global_load_dwordx2 (non-sinkable), double-buffered
// register stash; superstep s+1's loads issued right AFTER the barrier
// (max issue->wait distance); counted s_waitcnt vmcnt(25) at s+1's top
// retires exactly the loads (25 newest outstanding = s's stores).
// lgkm-only barriers keep vmem in flight across the join.
// Geometry: block=(bc, 64-wide f-tile), 512 thr = 8 waves, 25 rows/wave,
// 5x200-row supersteps. x read from HBM exactly once. 256 blocks.

#define EPS_F 1e-14f

constexpr int B = 16, C = 2, T = 1000, F = 481;
constexpr int BC = B * C;        // 32
constexpr int FW = 64;           // f-tile width = one wave
constexpr int NTILE = 8;         // ceil(481/64)
constexpr int WV = 8;            // waves per block
constexpr int RW = 25;           // rows per wave per superstep
constexpr int RSTEP = WV * RW;   // 200
constexpr int NSUP = T / RSTEP;  // 5 (exact)
constexpr int ROWS = F * 2;      // 962 floats per t-row

static_assert(RW == 25, "vmcnt(25) literal below assumes RW==25");

__device__ __forceinline__ float2 gload2(const float* p) {
    float2 r;
    asm volatile("global_load_dwordx2 %0, %1, off"
                 : "=v"(r) : "v"(p) : "memory");
    return r;
}

#define WAITV(n)                                                   \
  do {                                                             \
    asm volatile("s_waitcnt vmcnt(" #n ")" ::: "memory");          \
    __builtin_amdgcn_sched_barrier(0);                             \
  } while (0)

#define LOADG(buf, sidx)                                           \
  {                                                                \
    const float* _xp = xp0 + (size_t)((sidx) * RSTEP) * ROWS;      \
    _Pragma("unroll")                                              \
    for (int j = 0; j < RW; ++j)                                   \
      (buf)[j] = gload2(_xp + (size_t)j * ROWS);                   \
  }

// One superstep, ONE barrier. Entry: cur holds loads_s (after WAITV).
#define STEP(sidx, cur, nxt, do_preload)                                     \
  {                                                                          \
    const int par = (sidx) & 1;                                              \
    float Cl = 0.0f;                                                         \
    _Pragma("unroll")                                                        \
    for (int j = 0; j < RW; ++j) {                                           \
      float m = fmaxf(fmaf((cur)[j].x, (cur)[j].x, (cur)[j].y * (cur)[j].y), \
                      EPS_F);                                                \
      Cl = fmaf(0.99f, Cl, 0.01f * __builtin_amdgcn_sqrtf(m));               \
    }                                                                        \
    lds_c[par][w][fx] = Cl;                                                  \
    asm volatile("s_waitcnt lgkmcnt(0)" ::: "memory");                       \
    __builtin_amdgcn_s_barrier();                                            \
    if (do_preload) LOADG(nxt, (sidx) + 1);                                  \
    float sloc = carry[par][fx];                                             \
    _Pragma("unroll")                                                        \
    for (int jw = 0; jw < WV - 1; ++jw)                                      \
      if (jw < w) sloc = fmaf(A25, sloc, lds_c[par][jw][fx]);                \
    if (w == WV - 1) carry[par ^ 1][fx] = fmaf(A25, sloc, Cl);               \
    float* _op = op0 + (size_t)((sidx) * RSTEP) * ROWS;                      \
    _Pragma("unroll")                                                        \
    for (int j = 0; j < RW; ++j) {                                           \
      float2 v = (cur)[j];                                                   \
      float m = fmaxf(fmaf(v.x, v.x, v.y * v.y), EPS_F);                     \
      sloc = fmaf(0.99f, sloc, 0.01f * __builtin_amdgcn_sqrtf(m));           \
      const float inv = __builtin_amdgcn_rsqf(sloc);                         \
      float2 o;                                                              \
      o.x = v.x * inv;                                                       \
      o.y = v.y * inv;                                                       \
      if (act) *(float2*)(_op + (size_t)j * ROWS) = o;                       \
    }                                                                        \
  }

__global__ __launch_bounds__(512, 2)
void k_fused(const float* __restrict__ x, const float* __restrict__ init_state,
             float* __restrict__ out) {
    __shared__ float lds_c[2][WV][FW];
    __shared__ float carry[2][FW];

    const int fx   = threadIdx.x & (FW - 1);
    const int w    = threadIdx.x >> 6;
    const int bc   = blockIdx.x & (BC - 1);
    const int tile = blockIdx.x >> 5;
    const int f    = tile * FW + fx;
    const bool act = (f < F);
    const int fc   = act ? f : (F - 1);   // clamped load address (no OOB)

    double q = 1.0;
    for (int i = 0; i < RW; ++i) q *= 0.99;
    const float A25 = (float)q;

    if (threadIdx.x < FW) carry[0][fx] = act ? init_state[f] : 1.0f;

    const float* xp0 = x   + ((size_t)(bc * T + w * RW) * F + fc) * 2;
    float*       op0 = out + ((size_t)(bc * T + w * RW) * F + f) * 2;

    float2 vA[RW], vB[RW];

    LOADG(vA, 0);
    WAITV(0);  STEP(0, vA, vB, true);
    WAITV(25); STEP(1, vB, vA, true);
    WAITV(25); STEP(2, vA, vB, true);
    WAITV(25); STEP(3, vB, vA, true);
    WAITV(25); STEP(4, vA, vB, false);
}

extern "C" void kernel_launch(void* const* d_in, const int* in_sizes, int n_in,
                              void* d_out, int out_size, void* d_ws, size_t ws_size,
                              hipStream_t stream) {
    const float* x          = (const float*)d_in[0];
    const float* init_state = (const float*)d_in[1];
    float* out = (float*)d_out;

    k_fused<<<dim3(NTILE * BC), 512, 0, stream>>>(x, init_state, out);
}